// Round 18
// baseline (195.472 us; speedup 1.0000x reference)
//
#include <hip/hip_runtime.h>
#include <hip/hip_bf16.h>

#define CIN 32
#define COUT 64
#define SCHUNK 1024
#define T_TILES 8

typedef __attribute__((ext_vector_type(8))) short bf16x8;
typedef __attribute__((ext_vector_type(4))) float f32x4;

__device__ inline short bf16r(float x) {
    unsigned u = __float_as_uint(x);
    return (short)((u + 0x7FFFu + ((u >> 16) & 1u)) >> 16);
}

__device__ inline unsigned pk2(float lo, float hi) {
    __hip_bfloat162 t = __float22bfloat162_rn(make_float2(lo, hi));
    return *(unsigned*)&t;
}

// ---------------------------------------------------------------------------
// Fused prep: [0,nbp) featb 64B rows + pbb | [+B1) per-block bucket hist
// (LDS only -> mat[blk][bkt]) | [+nbm) gather out_bxyz | [+32) pack weights.
__global__ void prep_kernel(const int4* __restrict__ e_new4,
                            int* __restrict__ mat, int E16, int nbkt,
                            const float* __restrict__ W1,
                            const float* __restrict__ W2,
                            short* __restrict__ wpack,
                            const float4* __restrict__ bxyz4,
                            const int* __restrict__ sidx,
                            float4* __restrict__ out_bxyz,
                            const float* __restrict__ feat,
                            uint4* __restrict__ featb,
                            uint2* __restrict__ pbb,
                            int M, int N, int nbp, int B1, int nbm) {
    __shared__ int h[512];
    int b = blockIdx.x, tid = threadIdx.x;
    if (b < nbp) {
        int p = b * 256 + tid;
        if (p < N) {
            const float4* s = (const float4*)(feat + (size_t)p * CIN);
            float4 f0 = s[0], f1 = s[1], f2 = s[2], f3 = s[3];
            float4 f4 = s[4], f5 = s[5], f6 = s[6], f7 = s[7];
            uint4* d = featb + (size_t)p * 4;
            d[0] = make_uint4(pk2(f0.x, f0.y), pk2(f0.z, f0.w), pk2(f1.x, f1.y), pk2(f1.z, f1.w));
            d[1] = make_uint4(pk2(f2.x, f2.y), pk2(f2.z, f2.w), pk2(f3.x, f3.y), pk2(f3.z, f3.w));
            d[2] = make_uint4(pk2(f4.x, f4.y), pk2(f4.z, f4.w), pk2(f5.x, f5.y), pk2(f5.z, f5.w));
            d[3] = make_uint4(pk2(f6.x, f6.y), pk2(f6.z, f6.w), pk2(f7.x, f7.y), pk2(f7.z, f7.w));
            float4 pb = bxyz4[p];
            pbb[p] = make_uint2(pk2(pb.y, pb.z), pk2(pb.w, 0.f));
        }
    } else if (b < nbp + B1) {
        int blk = b - nbp;
        h[tid] = 0; h[tid + 256] = 0;
        __syncthreads();
        int i = blk * 256 + tid;
        if (i < E16) {
            int4 n0 = e_new4[i * 4 + 0];
            int4 n1 = e_new4[i * 4 + 1];
            int4 n2 = e_new4[i * 4 + 2];
            int4 n3 = e_new4[i * 4 + 3];
            atomicAdd(&h[n0.x >> 8], 1); atomicAdd(&h[n0.y >> 8], 1);
            atomicAdd(&h[n0.z >> 8], 1); atomicAdd(&h[n0.w >> 8], 1);
            atomicAdd(&h[n1.x >> 8], 1); atomicAdd(&h[n1.y >> 8], 1);
            atomicAdd(&h[n1.z >> 8], 1); atomicAdd(&h[n1.w >> 8], 1);
            atomicAdd(&h[n2.x >> 8], 1); atomicAdd(&h[n2.y >> 8], 1);
            atomicAdd(&h[n2.z >> 8], 1); atomicAdd(&h[n2.w >> 8], 1);
            atomicAdd(&h[n3.x >> 8], 1); atomicAdd(&h[n3.y >> 8], 1);
            atomicAdd(&h[n3.z >> 8], 1); atomicAdd(&h[n3.w >> 8], 1);
        }
        __syncthreads();
        if (tid < nbkt)       mat[(size_t)blk * nbkt + tid] = h[tid];
        if (tid + 256 < nbkt) mat[(size_t)blk * nbkt + tid + 256] = h[tid + 256];
    } else if (b < nbp + B1 + nbm) {
        int i = (b - nbp - B1) * 256 + tid;
        if (i < M) out_bxyz[i] = bxyz4[sidx[i]];
    } else {
        int t = (b - nbp - B1 - nbm) * 256 + tid;   // 8192 exactly
        int e = t & 7, l = (t >> 3) & 63, f = t >> 9;
        int g = l >> 4, n16 = l & 15;
        int kc = (f & 7) >> 2, nt = f & 3;
        int k = kc * 32 + g * 8 + e;
        int n = nt * 16 + n16;
        float v;
        if (f < 8) v = (k < CIN + 3) ? W1[k * COUT + n] : 0.f;
        else       v = W2[k * COUT + n];
        wpack[t] = bf16r(v);
    }
}

// ---------------------------------------------------------------------------
// Column scan of mat (per-bucket, over blocks) -> exclusive prefixes + totals.
__global__ void p1s1_kernel(int* __restrict__ mat, int* __restrict__ total,
                            int B1, int nbkt) {
    __shared__ int lds[256];
    int k = blockIdx.x, t = threadIdx.x;
    int i0 = 2 * t, i1 = 2 * t + 1;
    int x0 = (i0 < B1) ? mat[(size_t)i0 * nbkt + k] : 0;
    int x1 = (i1 < B1) ? mat[(size_t)i1 * nbkt + k] : 0;
    int s = x0 + x1;
    int val = s;
    lds[t] = val; __syncthreads();
    for (int off = 1; off < 256; off <<= 1) {
        int x = (t >= off) ? lds[t - off] : 0;
        __syncthreads();
        val += x; lds[t] = val;
        __syncthreads();
    }
    int ex = val - s;
    if (i0 < B1) mat[(size_t)i0 * nbkt + k] = ex;
    if (i1 < B1) mat[(size_t)i1 * nbkt + k] = ex + x0;
    if (t == 255) total[k] = val;
}

// Scan of bucket totals -> base[0..nbkt] (exclusive; base[nbkt] = E).
__global__ void p1s2_kernel(const int* __restrict__ total,
                            int* __restrict__ base, int nbkt) {
    __shared__ int lds[256];
    int t = threadIdx.x;
    int i0 = 2 * t, i1 = 2 * t + 1;
    int x0 = (i0 < nbkt) ? total[i0] : 0;
    int x1 = (i1 < nbkt) ? total[i1] : 0;
    int s = x0 + x1;
    int val = s;
    lds[t] = val; __syncthreads();
    for (int off = 1; off < 256; off <<= 1) {
        int x = (t >= off) ? lds[t - off] : 0;
        __syncthreads();
        val += x; lds[t] = val;
        __syncthreads();
    }
    int ex = val - s;
    if (i0 < nbkt) base[i0] = ex;
    if (i1 < nbkt) base[i1] = ex + x0;
    if (t == 255) base[nbkt] = val;
}

// ---------------------------------------------------------------------------
// Bucket scatter: LDS cursors seeded from base+mat. Records (seg, ep) land
// bucket-contiguous. No global atomics.
__global__ void p1c_kernel(const int4* __restrict__ e_new4,
                           const int4* __restrict__ e_pt4,
                           const int* __restrict__ mat,
                           const int* __restrict__ base,
                           uint2* __restrict__ rec, int E16, int nbkt) {
    __shared__ int cur[512];
    int blk = blockIdx.x, tid = threadIdx.x;
    if (tid < nbkt)       cur[tid]       = base[tid]       + mat[(size_t)blk * nbkt + tid];
    if (tid + 256 < nbkt) cur[tid + 256] = base[tid + 256] + mat[(size_t)blk * nbkt + tid + 256];
    __syncthreads();
    int i = blk * 256 + tid;
    if (i >= E16) return;
    int4 n0 = e_new4[i * 4 + 0], n1 = e_new4[i * 4 + 1];
    int4 n2 = e_new4[i * 4 + 2], n3 = e_new4[i * 4 + 3];
    int4 p0 = e_pt4[i * 4 + 0],  p1 = e_pt4[i * 4 + 1];
    int4 p2 = e_pt4[i * 4 + 2],  p3 = e_pt4[i * 4 + 3];
    int sg[16] = {n0.x, n0.y, n0.z, n0.w, n1.x, n1.y, n1.z, n1.w,
                  n2.x, n2.y, n2.z, n2.w, n3.x, n3.y, n3.z, n3.w};
    int ep[16] = {p0.x, p0.y, p0.z, p0.w, p1.x, p1.y, p1.z, p1.w,
                  p2.x, p2.y, p2.z, p2.w, p3.x, p3.y, p3.z, p3.w};
#pragma unroll
    for (int k = 0; k < 16; ++k) {
        int pos = atomicAdd(&cur[sg[k] >> 8], 1);
        rec[pos] = make_uint2((unsigned)sg[k], (unsigned)ep[k]);
    }
}

// ---------------------------------------------------------------------------
// Per-bucket segment histogram (LDS) -> counts[s] (coalesced write).
__global__ void p2a_kernel(const uint2* __restrict__ rec,
                           const int* __restrict__ base,
                           int* __restrict__ counts, int M) {
    __shared__ int h[256];
    int k = blockIdx.x, t = threadIdx.x;
    h[t] = 0; __syncthreads();
    int st = base[k], en = base[k + 1];
    for (int j = st + t; j < en; j += 256)
        atomicAdd(&h[rec[j].x & 255], 1);
    __syncthreads();
    int s = k * 256 + t;
    if (s < M) counts[s] = h[t];
}

// ---------------------------------------------------------------------------
// Scan of per-seg TILE counts ((cnt+15)/16) -> padded tile starts.
__global__ void scanA_kernel(const int* __restrict__ counts,
                             int* __restrict__ row1,
                             int* __restrict__ sums, int M) {
    __shared__ int lds[256];
    int t = threadIdx.x, blk = blockIdx.x;
    int bse = blk * SCHUNK + t * 4;
    int v0 = (bse + 0 < M) ? (counts[bse + 0] + 15) >> 4 : 0;
    int v1 = (bse + 1 < M) ? (counts[bse + 1] + 15) >> 4 : 0;
    int v2 = (bse + 2 < M) ? (counts[bse + 2] + 15) >> 4 : 0;
    int v3 = (bse + 3 < M) ? (counts[bse + 3] + 15) >> 4 : 0;
    int s = v0 + v1 + v2 + v3;
    int val = s;
    lds[t] = val; __syncthreads();
    for (int off = 1; off < 256; off <<= 1) {
        int x = (t >= off) ? lds[t - off] : 0;
        __syncthreads();
        val += x; lds[t] = val;
        __syncthreads();
    }
    int ex = val - s;
    if (bse + 0 < M) row1[bse + 0] = ex + v0;
    if (bse + 1 < M) row1[bse + 1] = ex + v0 + v1;
    if (bse + 2 < M) row1[bse + 2] = ex + v0 + v1 + v2;
    if (bse + 3 < M) row1[bse + 3] = ex + s;
    if (t == 255) sums[blk] = val;
}

__global__ void scanC_kernel(int* __restrict__ row1,
                             const int* __restrict__ sums,
                             int* __restrict__ tstart, int M) {
    __shared__ int lds[256];
    int blk = blockIdx.x, t = threadIdx.x;
    lds[t] = (t < blk) ? sums[t] : 0;
    __syncthreads();
    for (int off = 128; off > 0; off >>= 1) {
        if (t < off) lds[t] += lds[t + off];
        __syncthreads();
    }
    int off0 = lds[0];
    if (blk == 0 && t == 0) tstart[0] = 0;
    int bse = blk * SCHUNK + t * 4;
#pragma unroll
    for (int i = 0; i < 4; ++i)
        if (bse + i < M) row1[bse + i] += off0;
}

// ---------------------------------------------------------------------------
// Per-bucket ticket + place + padfill. LDS returning atomics only.
__global__ void p2b_kernel(const uint2* __restrict__ rec,
                           const int* __restrict__ base,
                           const int* __restrict__ tstart,
                           int* __restrict__ csr_ep,
                           int* __restrict__ tile_seg, int M) {
    __shared__ int cur[256];
    int k = blockIdx.x, t = threadIdx.x;
    cur[t] = 0; __syncthreads();
    int st = base[k], en = base[k + 1];
    for (int j = st + t; j < en; j += 256) {
        uint2 r = rec[j];
        int s = (int)r.x;
        int tk = atomicAdd(&cur[s & 255], 1);
        csr_ep[(size_t)tstart[s] * 16 + tk] = (int)r.y;
    }
    __syncthreads();
    int s = k * 256 + t;
    if (s < M) {
        int cnt = cur[t];
        if (cnt) {
            int tst = tstart[s];
            int ntl = (cnt + 15) >> 4;
            int prow = tst * 16;
            int ep0 = csr_ep[prow];
            for (int j = cnt; j < ntl * 16; ++j) csr_ep[prow + j] = ep0;
            for (int j = 0; j < ntl; ++j) tile_seg[tst + j] = s;
        }
    }
}

// ---------------------------------------------------------------------------
// Aggregation: R17 structure (zero-conflict bf16 staging) with R16's leaner
// LOADSLOT: rel computed directly into a2 on g==0 lanes (predicated pbb load),
// accumulator init = plain b1v (no per-tile bias fold; -20 VGPR, -12 FMA/tile).
__global__ __launch_bounds__(256, 3)
void agg_kernel(const uint4* __restrict__ featb,    // [N][4] 64B rows
                const uint2* __restrict__ pbb,      // [N] bf16 xyz
                const int* __restrict__ csr_ep,     // padded
                const int* __restrict__ tile_seg,   // [ntiles]
                const int* __restrict__ ntiles_ptr, // = &tstart[M]
                const bf16x8* __restrict__ wpack,
                const float* __restrict__ b1,
                const float* __restrict__ b2,
                const float4* __restrict__ new_bxyz4,
                float* __restrict__ out_feat) {
    __shared__ char   h1buf[4][2048];  // per-wave 16x64 bf16, swizzled
    __shared__ bf16x8 w2lds[512];      // 8 KB block-shared

    const int ntiles = ntiles_ptr[0];
    if (blockIdx.x * 4 * T_TILES >= ntiles) return;

    w2lds[threadIdx.x]       = wpack[512 + threadIdx.x];
    w2lds[threadIdx.x + 256] = wpack[768 + threadIdx.x];
    __syncthreads();

    const int lane = threadIdx.x & 63;
    const int w    = threadIdx.x >> 6;
    const int m    = lane & 15;
    const int g    = lane >> 4;

    int wid = blockIdx.x * 4 + w;
    int t0  = wid * T_TILES;
    int niter = min(T_TILES, ntiles - t0);
    if (niter <= 0) return;

    bf16x8 w1b[8];
#pragma unroll
    for (int f = 0; f < 8; ++f) w1b[f] = wpack[f * 64 + lane];

    float b1v[4], b2v[4];
#pragma unroll
    for (int nt = 0; nt < 4; ++nt) {
        int col = nt * 16 + m;
        b1v[nt] = b1[col];
        b2v[nt] = b2[col];
    }

    char* h1p = h1buf[w];
    int wA[16];
#pragma unroll
    for (int q = 0; q < 4; ++q) {
        int row = g * 4 + q;
        int kk = (row & 7) << 4;
#pragma unroll
        for (int nt = 0; nt < 4; ++nt)
            wA[q * 4 + nt] = (row * 128 + (m + nt * 16) * 2) ^ kk;
    }
    const int rb0 = (m * 128 + g * 16) ^ ((m & 7) << 4);
    const int rb1 = (m * 128 + (4 + g) * 16) ^ ((m & 7) << 4);

    int* outI = (int*)out_feat;

    int seg0, seg1;
    bf16x8 a10, a11;
    unsigned ax0, ay0, ax1, ay1;

#define LOADSLOT(S, TI)                                                       \
    do {                                                                      \
        int ti_ = min((TI), ntiles - 1);                                      \
        seg##S = tile_seg[ti_];                                               \
        unsigned ep_ = (unsigned)csr_ep[ti_ * 16 + m];                        \
        a1##S = ((const bf16x8*)featb)[(size_t)ep_ * 4 + g];                  \
        ax##S = 0; ay##S = 0;                                                 \
        if (g == 0) {                                                         \
            uint2 pb_ = pbb[ep_];                                             \
            float4 nb_ = new_bxyz4[seg##S];                                   \
            float py_ = __uint_as_float(pb_.x << 16);                         \
            float pz_ = __uint_as_float(pb_.x & 0xffff0000u);                 \
            float pw_ = __uint_as_float(pb_.y << 16);                         \
            ax##S = pk2(py_ - nb_.y, pz_ - nb_.z);                            \
            ay##S = (unsigned)(unsigned short)bf16r(pw_ - nb_.w);             \
        }                                                                     \
    } while (0)

#define COMPUTE(S)                                                            \
    do {                                                                      \
        bf16x8 a2 = {0, 0, 0, 0, 0, 0, 0, 0};                                 \
        if (g == 0) {                                                         \
            a2[0] = (short)(ax##S & 0xffffu);                                 \
            a2[1] = (short)(ax##S >> 16);                                     \
            a2[2] = (short)ay##S;                                             \
        }                                                                     \
        _Pragma("unroll")                                                     \
        for (int nt = 0; nt < 4; ++nt) {                                      \
            float be = b1v[nt];                                               \
            f32x4 cc = {be, be, be, be};                                      \
            cc = __builtin_amdgcn_mfma_f32_16x16x32_bf16(a1##S, w1b[nt], cc, 0, 0, 0); \
            cc = __builtin_amdgcn_mfma_f32_16x16x32_bf16(a2, w1b[4 + nt], cc, 0, 0, 0); \
            _Pragma("unroll")                                                 \
            for (int q = 0; q < 4; ++q) {                                     \
                unsigned hv = pk2(fmaxf(cc[q], 0.f), 0.f);                    \
                *(short*)(h1p + wA[q * 4 + nt]) = (short)(hv & 0xffffu);      \
            }                                                                 \
        }                                                                     \
        bf16x8 A30 = *(const bf16x8*)(h1p + rb0);                             \
        bf16x8 A31 = *(const bf16x8*)(h1p + rb1);                             \
        float vmax[4];                                                        \
        _Pragma("unroll")                                                     \
        for (int nt = 0; nt < 4; ++nt) {                                      \
            bf16x8 wf0 = w2lds[nt * 64 + lane];                               \
            bf16x8 wf1 = w2lds[(4 + nt) * 64 + lane];                         \
            f32x4 cc = {b2v[nt], b2v[nt], b2v[nt], b2v[nt]};                  \
            cc = __builtin_amdgcn_mfma_f32_16x16x32_bf16(A30, wf0, cc, 0, 0, 0); \
            cc = __builtin_amdgcn_mfma_f32_16x16x32_bf16(A31, wf1, cc, 0, 0, 0); \
            vmax[nt] = fmaxf(fmaxf(cc[0], cc[1]), fmaxf(cc[2], cc[3]));       \
        }                                                                     \
        _Pragma("unroll")                                                     \
        for (int nt = 0; nt < 4; ++nt) {                                      \
            float v = vmax[nt];                                               \
            v = fmaxf(v, __shfl_xor(v, 16));                                  \
            v = fmaxf(v, __shfl_xor(v, 32));                                  \
            vmax[nt] = v;                                                     \
        }                                                                     \
        float outv = (g == 0) ? vmax[0] : (g == 1) ? vmax[1]                  \
                   : (g == 2) ? vmax[2] : vmax[3];                            \
        outv = fmaxf(outv, 0.f);                                              \
        atomicMax(&outI[(size_t)seg##S * COUT + lane], __float_as_int(outv)); \
    } while (0)

    LOADSLOT(0, t0);
    int i = 0;
    for (;;) {
        if (i >= niter) break;
        LOADSLOT(1, t0 + i + 1);
        COMPUTE(0); ++i;
        if (i >= niter) break;
        LOADSLOT(0, t0 + i + 1);
        COMPUTE(1); ++i;
    }
#undef LOADSLOT
#undef COMPUTE
}

// ---------------------------------------------------------------------------
extern "C" void kernel_launch(void* const* d_in, const int* in_sizes, int n_in,
                              void* d_out, int out_size, void* d_ws, size_t ws_size,
                              hipStream_t stream) {
    const float* bxyz   = (const float*)d_in[0];
    const float* feat   = (const float*)d_in[1];
    const int*   sidx   = (const int*)d_in[2];
    const int*   e_pt   = (const int*)d_in[3];
    const int*   e_new  = (const int*)d_in[4];
    const float* W1     = (const float*)d_in[5];
    const float* b1     = (const float*)d_in[6];
    const float* W2     = (const float*)d_in[7];
    const float* b2     = (const float*)d_in[8];

    const int N = in_sizes[0] / 4;
    const int M = in_sizes[2];
    const int E = in_sizes[3];

    float* out_bxyz = (float*)d_out;                 // [M][4]
    float* out_feat = out_bxyz + (size_t)M * 4;      // [M][64]

    const int E16  = E / 16;                         // E divisible by 16
    const int nbkt = (M + 255) >> 8;                 // 256 segments / bucket
    const int B1   = (E16 + 255) / 256;
    const int nbm  = (M + 255) / 256;
    const int nbp  = (N + 255) / 256;
    const int nchunks = (M + SCHUNK - 1) / SCHUNK;   // <=256 required

    // ws layout
    char* ws = (char*)d_ws;
    size_t off = 16384;                                        // wpack
    size_t o_mat = off;  off += ((size_t)B1 * nbkt * 4 + 63) & ~(size_t)63;
    size_t o_tot = off;  off += ((size_t)nbkt * 4 + 63) & ~(size_t)63;
    size_t o_bas = off;  off += ((size_t)(nbkt + 1) * 4 + 63) & ~(size_t)63;
    size_t o_cnt = off;  off += ((size_t)M * 4 + 63) & ~(size_t)63;
    size_t o_ts  = off;  off += (((size_t)M + 4) * 4 + 63) & ~(size_t)63;
    size_t o_sum = off;  off += 1024;
    size_t o_rec = off;  off += (size_t)E * 8;
    size_t csr_cap = (size_t)E + 15 * (size_t)M + 64;
    size_t o_csr = off;  off += csr_cap * 4;
    size_t o_tsg = off;  off += (csr_cap / 16 + 64) * 4;
    off = (off + 63) & ~(size_t)63;
    size_t o_pbb = off;  off += (size_t)N * 8;
    off = (off + 63) & ~(size_t)63;
    size_t o_fb  = off;  off += (size_t)N * 64;

    short* wpack    = (short*)ws;
    int*   mat      = (int*)(ws + o_mat);
    int*   total    = (int*)(ws + o_tot);
    int*   base     = (int*)(ws + o_bas);
    int*   counts   = (int*)(ws + o_cnt);
    int*   tstart   = (int*)(ws + o_ts);
    int*   sums     = (int*)(ws + o_sum);
    uint2* rec      = (uint2*)(ws + o_rec);
    int*   csr_ep   = (int*)(ws + o_csr);
    int*   tile_seg = (int*)(ws + o_tsg);
    uint2* pbb      = (uint2*)(ws + o_pbb);
    uint4* featb    = (uint4*)(ws + o_fb);
    int*   row1     = tstart + 1;

    hipMemsetAsync(out_feat, 0, (size_t)M * COUT * 4, stream);

    prep_kernel<<<nbp + B1 + nbm + 32, 256, 0, stream>>>(
        (const int4*)e_new, mat, E16, nbkt,
        W1, W2, wpack, (const float4*)bxyz, sidx, (float4*)out_bxyz,
        feat, featb, pbb, M, N, nbp, B1, nbm);

    p1s1_kernel<<<nbkt, 256, 0, stream>>>(mat, total, B1, nbkt);
    p1s2_kernel<<<1, 256, 0, stream>>>(total, base, nbkt);
    p1c_kernel<<<B1, 256, 0, stream>>>(
        (const int4*)e_new, (const int4*)e_pt, mat, base, rec, E16, nbkt);

    p2a_kernel<<<nbkt, 256, 0, stream>>>(rec, base, counts, M);
    scanA_kernel<<<nchunks, 256, 0, stream>>>(counts, row1, sums, M);
    scanC_kernel<<<nchunks, 256, 0, stream>>>(row1, sums, tstart, M);
    p2b_kernel<<<nbkt, 256, 0, stream>>>(rec, base, tstart, csr_ep, tile_seg, M);

    int maxtiles = E / 16 + M;
    int nblocks  = (maxtiles + 4 * T_TILES - 1) / (4 * T_TILES);
    agg_kernel<<<nblocks, 256, 0, stream>>>(
        featb, pbb, csr_ep, tile_seg, tstart + M, (const bf16x8*)wpack,
        b1, b2, (const float4*)out_bxyz, out_feat);
}

// Round 19
// 181.763 us; speedup vs baseline: 1.0754x; 1.0754x over previous
//
#include <hip/hip_runtime.h>
#include <hip/hip_bf16.h>

#define CIN 32
#define COUT 64
#define SCHUNK 1024
#define T_TILES 8

typedef __attribute__((ext_vector_type(8))) short bf16x8;
typedef __attribute__((ext_vector_type(4))) float f32x4;

__device__ inline short bf16r(float x) {
    unsigned u = __float_as_uint(x);
    return (short)((u + 0x7FFFu + ((u >> 16) & 1u)) >> 16);
}

__device__ inline unsigned pk2(float lo, float hi) {
    __hip_bfloat162 t = __float22bfloat162_rn(make_float2(lo, hi));
    return *(unsigned*)&t;
}

// ---------------------------------------------------------------------------
// Fused prep: [0,nbp) featb 64B rows + pbb | [+B1) per-block bucket hist
// (LDS only -> mat[blk][bkt]) | [+nbm) gather out_bxyz | [+32) pack weights.
__global__ void prep_kernel(const int4* __restrict__ e_new4,
                            int* __restrict__ mat, int E16, int nbkt,
                            const float* __restrict__ W1,
                            const float* __restrict__ W2,
                            short* __restrict__ wpack,
                            const float4* __restrict__ bxyz4,
                            const int* __restrict__ sidx,
                            float4* __restrict__ out_bxyz,
                            const float* __restrict__ feat,
                            uint4* __restrict__ featb,
                            uint2* __restrict__ pbb,
                            int M, int N, int nbp, int B1, int nbm) {
    __shared__ int h[512];
    int b = blockIdx.x, tid = threadIdx.x;
    if (b < nbp) {
        int p = b * 256 + tid;
        if (p < N) {
            const float4* s = (const float4*)(feat + (size_t)p * CIN);
            float4 f0 = s[0], f1 = s[1], f2 = s[2], f3 = s[3];
            float4 f4 = s[4], f5 = s[5], f6 = s[6], f7 = s[7];
            uint4* d = featb + (size_t)p * 4;
            d[0] = make_uint4(pk2(f0.x, f0.y), pk2(f0.z, f0.w), pk2(f1.x, f1.y), pk2(f1.z, f1.w));
            d[1] = make_uint4(pk2(f2.x, f2.y), pk2(f2.z, f2.w), pk2(f3.x, f3.y), pk2(f3.z, f3.w));
            d[2] = make_uint4(pk2(f4.x, f4.y), pk2(f4.z, f4.w), pk2(f5.x, f5.y), pk2(f5.z, f5.w));
            d[3] = make_uint4(pk2(f6.x, f6.y), pk2(f6.z, f6.w), pk2(f7.x, f7.y), pk2(f7.z, f7.w));
            float4 pb = bxyz4[p];
            pbb[p] = make_uint2(pk2(pb.y, pb.z), pk2(pb.w, 0.f));
        }
    } else if (b < nbp + B1) {
        int blk = b - nbp;
        h[tid] = 0; h[tid + 256] = 0;
        __syncthreads();
        int i = blk * 256 + tid;
        if (i < E16) {
            int4 n0 = e_new4[i * 4 + 0];
            int4 n1 = e_new4[i * 4 + 1];
            int4 n2 = e_new4[i * 4 + 2];
            int4 n3 = e_new4[i * 4 + 3];
            atomicAdd(&h[n0.x >> 8], 1); atomicAdd(&h[n0.y >> 8], 1);
            atomicAdd(&h[n0.z >> 8], 1); atomicAdd(&h[n0.w >> 8], 1);
            atomicAdd(&h[n1.x >> 8], 1); atomicAdd(&h[n1.y >> 8], 1);
            atomicAdd(&h[n1.z >> 8], 1); atomicAdd(&h[n1.w >> 8], 1);
            atomicAdd(&h[n2.x >> 8], 1); atomicAdd(&h[n2.y >> 8], 1);
            atomicAdd(&h[n2.z >> 8], 1); atomicAdd(&h[n2.w >> 8], 1);
            atomicAdd(&h[n3.x >> 8], 1); atomicAdd(&h[n3.y >> 8], 1);
            atomicAdd(&h[n3.z >> 8], 1); atomicAdd(&h[n3.w >> 8], 1);
        }
        __syncthreads();
        if (tid < nbkt)       mat[(size_t)blk * nbkt + tid] = h[tid];
        if (tid + 256 < nbkt) mat[(size_t)blk * nbkt + tid + 256] = h[tid + 256];
    } else if (b < nbp + B1 + nbm) {
        int i = (b - nbp - B1) * 256 + tid;
        if (i < M) out_bxyz[i] = bxyz4[sidx[i]];
    } else {
        int t = (b - nbp - B1 - nbm) * 256 + tid;   // 8192 exactly
        int e = t & 7, l = (t >> 3) & 63, f = t >> 9;
        int g = l >> 4, n16 = l & 15;
        int kc = (f & 7) >> 2, nt = f & 3;
        int k = kc * 32 + g * 8 + e;
        int n = nt * 16 + n16;
        float v;
        if (f < 8) v = (k < CIN + 3) ? W1[k * COUT + n] : 0.f;
        else       v = W2[k * COUT + n];
        wpack[t] = bf16r(v);
    }
}

// ---------------------------------------------------------------------------
// Column scan of mat (per-bucket, over blocks) -> exclusive prefixes + totals.
__global__ void p1s1_kernel(int* __restrict__ mat, int* __restrict__ total,
                            int B1, int nbkt) {
    __shared__ int lds[256];
    int k = blockIdx.x, t = threadIdx.x;
    int i0 = 2 * t, i1 = 2 * t + 1;
    int x0 = (i0 < B1) ? mat[(size_t)i0 * nbkt + k] : 0;
    int x1 = (i1 < B1) ? mat[(size_t)i1 * nbkt + k] : 0;
    int s = x0 + x1;
    int val = s;
    lds[t] = val; __syncthreads();
    for (int off = 1; off < 256; off <<= 1) {
        int x = (t >= off) ? lds[t - off] : 0;
        __syncthreads();
        val += x; lds[t] = val;
        __syncthreads();
    }
    int ex = val - s;
    if (i0 < B1) mat[(size_t)i0 * nbkt + k] = ex;
    if (i1 < B1) mat[(size_t)i1 * nbkt + k] = ex + x0;
    if (t == 255) total[k] = val;
}

// Scan of bucket totals -> base[0..nbkt] (exclusive; base[nbkt] = E).
__global__ void p1s2_kernel(const int* __restrict__ total,
                            int* __restrict__ base, int nbkt) {
    __shared__ int lds[256];
    int t = threadIdx.x;
    int i0 = 2 * t, i1 = 2 * t + 1;
    int x0 = (i0 < nbkt) ? total[i0] : 0;
    int x1 = (i1 < nbkt) ? total[i1] : 0;
    int s = x0 + x1;
    int val = s;
    lds[t] = val; __syncthreads();
    for (int off = 1; off < 256; off <<= 1) {
        int x = (t >= off) ? lds[t - off] : 0;
        __syncthreads();
        val += x; lds[t] = val;
        __syncthreads();
    }
    int ex = val - s;
    if (i0 < nbkt) base[i0] = ex;
    if (i1 < nbkt) base[i1] = ex + x0;
    if (t == 255) base[nbkt] = val;
}

// ---------------------------------------------------------------------------
// Bucket scatter: LDS cursors seeded from base+mat. Records (seg, ep) land
// bucket-contiguous. No global atomics.
__global__ void p1c_kernel(const int4* __restrict__ e_new4,
                           const int4* __restrict__ e_pt4,
                           const int* __restrict__ mat,
                           const int* __restrict__ base,
                           uint2* __restrict__ rec, int E16, int nbkt) {
    __shared__ int cur[512];
    int blk = blockIdx.x, tid = threadIdx.x;
    if (tid < nbkt)       cur[tid]       = base[tid]       + mat[(size_t)blk * nbkt + tid];
    if (tid + 256 < nbkt) cur[tid + 256] = base[tid + 256] + mat[(size_t)blk * nbkt + tid + 256];
    __syncthreads();
    int i = blk * 256 + tid;
    if (i >= E16) return;
    int4 n0 = e_new4[i * 4 + 0], n1 = e_new4[i * 4 + 1];
    int4 n2 = e_new4[i * 4 + 2], n3 = e_new4[i * 4 + 3];
    int4 p0 = e_pt4[i * 4 + 0],  p1 = e_pt4[i * 4 + 1];
    int4 p2 = e_pt4[i * 4 + 2],  p3 = e_pt4[i * 4 + 3];
    int sg[16] = {n0.x, n0.y, n0.z, n0.w, n1.x, n1.y, n1.z, n1.w,
                  n2.x, n2.y, n2.z, n2.w, n3.x, n3.y, n3.z, n3.w};
    int ep[16] = {p0.x, p0.y, p0.z, p0.w, p1.x, p1.y, p1.z, p1.w,
                  p2.x, p2.y, p2.z, p2.w, p3.x, p3.y, p3.z, p3.w};
#pragma unroll
    for (int k = 0; k < 16; ++k) {
        int pos = atomicAdd(&cur[sg[k] >> 8], 1);
        rec[pos] = make_uint2((unsigned)sg[k], (unsigned)ep[k]);
    }
}

// ---------------------------------------------------------------------------
// Per-bucket segment histogram (LDS) -> counts[s] (coalesced write).
__global__ void p2a_kernel(const uint2* __restrict__ rec,
                           const int* __restrict__ base,
                           int* __restrict__ counts, int M) {
    __shared__ int h[256];
    int k = blockIdx.x, t = threadIdx.x;
    h[t] = 0; __syncthreads();
    int st = base[k], en = base[k + 1];
    for (int j = st + t; j < en; j += 256)
        atomicAdd(&h[rec[j].x & 255], 1);
    __syncthreads();
    int s = k * 256 + t;
    if (s < M) counts[s] = h[t];
}

// ---------------------------------------------------------------------------
// Scan of per-seg TILE counts ((cnt+15)/16) -> padded tile starts.
__global__ void scanA_kernel(const int* __restrict__ counts,
                             int* __restrict__ row1,
                             int* __restrict__ sums, int M) {
    __shared__ int lds[256];
    int t = threadIdx.x, blk = blockIdx.x;
    int bse = blk * SCHUNK + t * 4;
    int v0 = (bse + 0 < M) ? (counts[bse + 0] + 15) >> 4 : 0;
    int v1 = (bse + 1 < M) ? (counts[bse + 1] + 15) >> 4 : 0;
    int v2 = (bse + 2 < M) ? (counts[bse + 2] + 15) >> 4 : 0;
    int v3 = (bse + 3 < M) ? (counts[bse + 3] + 15) >> 4 : 0;
    int s = v0 + v1 + v2 + v3;
    int val = s;
    lds[t] = val; __syncthreads();
    for (int off = 1; off < 256; off <<= 1) {
        int x = (t >= off) ? lds[t - off] : 0;
        __syncthreads();
        val += x; lds[t] = val;
        __syncthreads();
    }
    int ex = val - s;
    if (bse + 0 < M) row1[bse + 0] = ex + v0;
    if (bse + 1 < M) row1[bse + 1] = ex + v0 + v1;
    if (bse + 2 < M) row1[bse + 2] = ex + v0 + v1 + v2;
    if (bse + 3 < M) row1[bse + 3] = ex + s;
    if (t == 255) sums[blk] = val;
}

__global__ void scanC_kernel(int* __restrict__ row1,
                             const int* __restrict__ sums,
                             int* __restrict__ tstart, int M) {
    __shared__ int lds[256];
    int blk = blockIdx.x, t = threadIdx.x;
    lds[t] = (t < blk) ? sums[t] : 0;
    __syncthreads();
    for (int off = 128; off > 0; off >>= 1) {
        if (t < off) lds[t] += lds[t + off];
        __syncthreads();
    }
    int off0 = lds[0];
    if (blk == 0 && t == 0) tstart[0] = 0;
    int bse = blk * SCHUNK + t * 4;
#pragma unroll
    for (int i = 0; i < 4; ++i)
        if (bse + i < M) row1[bse + i] += off0;
}

// ---------------------------------------------------------------------------
// Per-bucket ticket + place + padfill. LDS returning atomics only; writes land
// in the bucket's contiguous csr window (L2-hot). Thread t then pads segment
// k*256+t (tile padding is duplicate-edge, max-idempotent) and fills tile_seg.
__global__ void p2b_kernel(const uint2* __restrict__ rec,
                           const int* __restrict__ base,
                           const int* __restrict__ tstart,
                           int* __restrict__ csr_ep,
                           int* __restrict__ tile_seg, int M) {
    __shared__ int cur[256];
    int k = blockIdx.x, t = threadIdx.x;
    cur[t] = 0; __syncthreads();
    int st = base[k], en = base[k + 1];
    for (int j = st + t; j < en; j += 256) {
        uint2 r = rec[j];
        int s = (int)r.x;
        int tk = atomicAdd(&cur[s & 255], 1);
        csr_ep[(size_t)tstart[s] * 16 + tk] = (int)r.y;
    }
    __syncthreads();
    int s = k * 256 + t;
    if (s < M) {
        int cnt = cur[t];
        if (cnt) {
            int tst = tstart[s];
            int ntl = (cnt + 15) >> 4;
            int prow = tst * 16;
            int ep0 = csr_ep[prow];
            for (int j = cnt; j < ntl * 16; ++j) csr_ep[prow + j] = ep0;
            for (int j = 0; j < ntl; ++j) tile_seg[tst + j] = s;
        }
    }
}

// ---------------------------------------------------------------------------
// Aggregation (R17 verbatim): wave owns T_TILES padded tiles; independent
// idempotent tiles end in a wave-coalesced atomicMax row. 2-slot ping-pong;
// w2 fragments in block-shared LDS. Layer1->2 transpose staged as BF16 with
// the R4-verified zero-conflict swizzle: byte=(row*128+col*2)^((row&7)<<4).
__global__ __launch_bounds__(256)
void agg_kernel(const uint4* __restrict__ featb,    // [N][4] 64B rows
                const uint2* __restrict__ pbb,      // [N] bf16 xyz
                const int* __restrict__ csr_ep,     // padded
                const int* __restrict__ tile_seg,   // [ntiles]
                const int* __restrict__ ntiles_ptr, // = &tstart[M]
                const bf16x8* __restrict__ wpack,
                const float* __restrict__ b1,
                const float* __restrict__ b2,
                const float* __restrict__ W1,
                const float4* __restrict__ new_bxyz4,
                float* __restrict__ out_feat) {
    __shared__ char   h1buf[4][2048];  // per-wave 16x64 bf16, swizzled
    __shared__ bf16x8 w2lds[512];      // 8 KB block-shared

    const int ntiles = ntiles_ptr[0];
    if (blockIdx.x * 4 * T_TILES >= ntiles) return;

    w2lds[threadIdx.x]       = wpack[512 + threadIdx.x];
    w2lds[threadIdx.x + 256] = wpack[768 + threadIdx.x];
    __syncthreads();

    const int lane = threadIdx.x & 63;
    const int w    = threadIdx.x >> 6;
    const int m    = lane & 15;
    const int g    = lane >> 4;

    int wid = blockIdx.x * 4 + w;
    int t0  = wid * T_TILES;
    int niter = min(T_TILES, ntiles - t0);
    if (niter <= 0) return;

    bf16x8 w1b[8];
#pragma unroll
    for (int f = 0; f < 8; ++f) w1b[f] = wpack[f * 64 + lane];

    float b1v[4], b2v[4], w1r0[4], w1r1[4], w1r2[4];
#pragma unroll
    for (int nt = 0; nt < 4; ++nt) {
        int col = nt * 16 + m;
        b1v[nt]  = b1[col];
        b2v[nt]  = b2[col];
        w1r0[nt] = W1[32 * COUT + col];
        w1r1[nt] = W1[33 * COUT + col];
        w1r2[nt] = W1[34 * COUT + col];
    }

    char* h1p = h1buf[w];
    // 16 loop-invariant write addresses (row=g*4+q, col=m+16nt), R4 swizzle
    int wA[16];
#pragma unroll
    for (int q = 0; q < 4; ++q) {
        int row = g * 4 + q;
        int kk = (row & 7) << 4;
#pragma unroll
        for (int nt = 0; nt < 4; ++nt)
            wA[q * 4 + nt] = (row * 128 + (m + nt * 16) * 2) ^ kk;
    }
    const int rb0 = (m * 128 + g * 16) ^ ((m & 7) << 4);
    const int rb1 = (m * 128 + (4 + g) * 16) ^ ((m & 7) << 4);

    int* outI = (int*)out_feat;

    int seg0, seg1;
    bf16x8 a10, a11;
    unsigned c4x0, c4y0, c4x1, c4y1;
    float be0[4], be1[4];

#define LOADSLOT(S, TI)                                                       \
    do {                                                                      \
        int ti_ = min((TI), ntiles - 1);                                      \
        seg##S = tile_seg[ti_];                                               \
        unsigned ep_ = (unsigned)csr_ep[ti_ * 16 + m];                        \
        uint2 c_ = pbb[ep_];                                                  \
        c4x##S = c_.x; c4y##S = c_.y;                                         \
        a1##S = ((const bf16x8*)featb)[(size_t)ep_ * 4 + g];                  \
        float4 nb_ = new_bxyz4[seg##S];                                       \
        _Pragma("unroll")                                                     \
        for (int nt = 0; nt < 4; ++nt)                                        \
            be##S[nt] = b1v[nt] - nb_.y * w1r0[nt] - nb_.z * w1r1[nt]         \
                                 - nb_.w * w1r2[nt];                          \
    } while (0)

#define COMPUTE(S)                                                            \
    do {                                                                      \
        bf16x8 a2 = {0, 0, 0, 0, 0, 0, 0, 0};                                 \
        if (g == 0) {                                                         \
            a2[0] = (short)(c4x##S & 0xffffu);                                \
            a2[1] = (short)(c4x##S >> 16);                                    \
            a2[2] = (short)(c4y##S & 0xffffu);                                \
        }                                                                     \
        _Pragma("unroll")                                                     \
        for (int nt = 0; nt < 4; ++nt) {                                      \
            float be = be##S[nt];                                             \
            f32x4 cc = {be, be, be, be};                                      \
            cc = __builtin_amdgcn_mfma_f32_16x16x32_bf16(a1##S, w1b[nt], cc, 0, 0, 0); \
            cc = __builtin_amdgcn_mfma_f32_16x16x32_bf16(a2, w1b[4 + nt], cc, 0, 0, 0); \
            _Pragma("unroll")                                                 \
            for (int q = 0; q < 4; ++q) {                                     \
                unsigned hv = pk2(fmaxf(cc[q], 0.f), 0.f);                    \
                *(short*)(h1p + wA[q * 4 + nt]) = (short)(hv & 0xffffu);      \
            }                                                                 \
        }                                                                     \
        bf16x8 A30 = *(const bf16x8*)(h1p + rb0);                             \
        bf16x8 A31 = *(const bf16x8*)(h1p + rb1);                             \
        float vmax[4];                                                        \
        _Pragma("unroll")                                                     \
        for (int nt = 0; nt < 4; ++nt) {                                      \
            bf16x8 wf0 = w2lds[nt * 64 + lane];                               \
            bf16x8 wf1 = w2lds[(4 + nt) * 64 + lane];                         \
            f32x4 cc = {b2v[nt], b2v[nt], b2v[nt], b2v[nt]};                  \
            cc = __builtin_amdgcn_mfma_f32_16x16x32_bf16(A30, wf0, cc, 0, 0, 0); \
            cc = __builtin_amdgcn_mfma_f32_16x16x32_bf16(A31, wf1, cc, 0, 0, 0); \
            vmax[nt] = fmaxf(fmaxf(cc[0], cc[1]), fmaxf(cc[2], cc[3]));       \
        }                                                                     \
        _Pragma("unroll")                                                     \
        for (int nt = 0; nt < 4; ++nt) {                                      \
            float v = vmax[nt];                                               \
            v = fmaxf(v, __shfl_xor(v, 16));                                  \
            v = fmaxf(v, __shfl_xor(v, 32));                                  \
            vmax[nt] = v;                                                     \
        }                                                                     \
        float outv = (g == 0) ? vmax[0] : (g == 1) ? vmax[1]                  \
                   : (g == 2) ? vmax[2] : vmax[3];                            \
        outv = fmaxf(outv, 0.f);                                              \
        atomicMax(&outI[(size_t)seg##S * COUT + lane], __float_as_int(outv)); \
    } while (0)

    LOADSLOT(0, t0);
    int i = 0;
    for (;;) {
        if (i >= niter) break;
        LOADSLOT(1, t0 + i + 1);
        COMPUTE(0); ++i;
        if (i >= niter) break;
        LOADSLOT(0, t0 + i + 1);
        COMPUTE(1); ++i;
    }
#undef LOADSLOT
#undef COMPUTE
}

// ---------------------------------------------------------------------------
extern "C" void kernel_launch(void* const* d_in, const int* in_sizes, int n_in,
                              void* d_out, int out_size, void* d_ws, size_t ws_size,
                              hipStream_t stream) {
    const float* bxyz   = (const float*)d_in[0];
    const float* feat   = (const float*)d_in[1];
    const int*   sidx   = (const int*)d_in[2];
    const int*   e_pt   = (const int*)d_in[3];
    const int*   e_new  = (const int*)d_in[4];
    const float* W1     = (const float*)d_in[5];
    const float* b1     = (const float*)d_in[6];
    const float* W2     = (const float*)d_in[7];
    const float* b2     = (const float*)d_in[8];

    const int N = in_sizes[0] / 4;
    const int M = in_sizes[2];
    const int E = in_sizes[3];

    float* out_bxyz = (float*)d_out;                 // [M][4]
    float* out_feat = out_bxyz + (size_t)M * 4;      // [M][64]

    const int E16  = E / 16;                         // E divisible by 16
    const int nbkt = (M + 255) >> 8;                 // 256 segments / bucket
    const int B1   = (E16 + 255) / 256;
    const int nbm  = (M + 255) / 256;
    const int nbp  = (N + 255) / 256;
    const int nchunks = (M + SCHUNK - 1) / SCHUNK;   // <=256 required

    // ws layout
    char* ws = (char*)d_ws;
    size_t off = 16384;                                        // wpack
    size_t o_mat = off;  off += ((size_t)B1 * nbkt * 4 + 63) & ~(size_t)63;
    size_t o_tot = off;  off += ((size_t)nbkt * 4 + 63) & ~(size_t)63;
    size_t o_bas = off;  off += ((size_t)(nbkt + 1) * 4 + 63) & ~(size_t)63;
    size_t o_cnt = off;  off += ((size_t)M * 4 + 63) & ~(size_t)63;
    size_t o_ts  = off;  off += (((size_t)M + 4) * 4 + 63) & ~(size_t)63;
    size_t o_sum = off;  off += 1024;
    size_t o_rec = off;  off += (size_t)E * 8;
    size_t csr_cap = (size_t)E + 15 * (size_t)M + 64;
    size_t o_csr = off;  off += csr_cap * 4;
    size_t o_tsg = off;  off += (csr_cap / 16 + 64) * 4;
    off = (off + 63) & ~(size_t)63;
    size_t o_pbb = off;  off += (size_t)N * 8;
    off = (off + 63) & ~(size_t)63;
    size_t o_fb  = off;  off += (size_t)N * 64;

    short* wpack    = (short*)ws;
    int*   mat      = (int*)(ws + o_mat);
    int*   total    = (int*)(ws + o_tot);
    int*   base     = (int*)(ws + o_bas);
    int*   counts   = (int*)(ws + o_cnt);
    int*   tstart   = (int*)(ws + o_ts);
    int*   sums     = (int*)(ws + o_sum);
    uint2* rec      = (uint2*)(ws + o_rec);
    int*   csr_ep   = (int*)(ws + o_csr);
    int*   tile_seg = (int*)(ws + o_tsg);
    uint2* pbb      = (uint2*)(ws + o_pbb);
    uint4* featb    = (uint4*)(ws + o_fb);
    int*   row1     = tstart + 1;

    hipMemsetAsync(out_feat, 0, (size_t)M * COUT * 4, stream);

    prep_kernel<<<nbp + B1 + nbm + 32, 256, 0, stream>>>(
        (const int4*)e_new, mat, E16, nbkt,
        W1, W2, wpack, (const float4*)bxyz, sidx, (float4*)out_bxyz,
        feat, featb, pbb, M, N, nbp, B1, nbm);

    p1s1_kernel<<<nbkt, 256, 0, stream>>>(mat, total, B1, nbkt);
    p1s2_kernel<<<1, 256, 0, stream>>>(total, base, nbkt);
    p1c_kernel<<<B1, 256, 0, stream>>>(
        (const int4*)e_new, (const int4*)e_pt, mat, base, rec, E16, nbkt);

    p2a_kernel<<<nbkt, 256, 0, stream>>>(rec, base, counts, M);
    scanA_kernel<<<nchunks, 256, 0, stream>>>(counts, row1, sums, M);
    scanC_kernel<<<nchunks, 256, 0, stream>>>(row1, sums, tstart, M);
    p2b_kernel<<<nbkt, 256, 0, stream>>>(rec, base, tstart, csr_ep, tile_seg, M);

    int maxtiles = E / 16 + M;
    int nblocks  = (maxtiles + 4 * T_TILES - 1) / (4 * T_TILES);
    agg_kernel<<<nblocks, 256, 0, stream>>>(
        featb, pbb, csr_ep, tile_seg, tstart + M, (const bf16x8*)wpack,
        b1, b2, W1, (const float4*)out_bxyz, out_feat);
}